// Round 1
// baseline (818.380 us; speedup 1.0000x reference)
//
#include <hip/hip_runtime.h>

#define XD 64
#define HD 128
#define RB 128          // rows per block
#define NTHREADS 512
#define WS_PITCH 136    // [128][136] bf16 rows (272B = 17 x 16B granules -> 2-way max)
#define WI_PITCH 72     // [128][72]  bf16 rows (144B = 9 x 16B granules)
#define OUT_PITCH 72

typedef __attribute__((ext_vector_type(8))) short short8;
typedef __attribute__((ext_vector_type(4))) float f32x4;

__device__ __forceinline__ short f2bf(float f) {
    union { float f; unsigned u; } v; v.f = f;
    unsigned r = (v.u + 0x7FFFu + ((v.u >> 16) & 1u)) >> 16;  // RTNE
    return (short)r;
}
__device__ __forceinline__ float bf2f(short s) {
    union { float f; unsigned u; } v;
    v.u = ((unsigned)(unsigned short)s) << 16;
    return v.f;
}

// LDS layout (bytes)
#define OFF_WS1 0
#define OFF_WS2 34816
#define OFF_WI  69632
#define OFF_H   88064
#define OFF_OUT 122880
#define OFF_ZC  141312
#define OFF_WIZ 141824
#define OFF_BI  142336
#define OFF_WF  142848
#define OFF_BS1 143360
#define OFF_BS2 143872
#define OFF_BF  144384
#define SMEM_BYTES 144400

__global__ __launch_bounds__(NTHREADS, 1) void gen_kernel(
    const float* __restrict__ x,   const float* __restrict__ z,
    const float* __restrict__ M,   const float* __restrict__ Wi,
    const float* __restrict__ bi,  const float* __restrict__ Ws1,
    const float* __restrict__ bs1, const float* __restrict__ Ws2,
    const float* __restrict__ bs2, const float* __restrict__ wf,
    const float* __restrict__ bf,  float* __restrict__ out)
{
    extern __shared__ char smem[];
    short* sWS1 = (short*)(smem + OFF_WS1);
    short* sWS2 = (short*)(smem + OFF_WS2);
    short* sWI  = (short*)(smem + OFF_WI);
    short* sH   = (short*)(smem + OFF_H);
    short* sOUT = (short*)(smem + OFF_OUT);
    float* sZC  = (float*)(smem + OFF_ZC);
    float* sWIZ = (float*)(smem + OFF_WIZ);
    float* sBI  = (float*)(smem + OFF_BI);
    float* sWF  = (float*)(smem + OFF_WF);
    float* sBS1 = (float*)(smem + OFF_BS1);
    float* sBS2 = (float*)(smem + OFF_BS2);
    float* sBF  = (float*)(smem + OFF_BF);

    const int tid  = threadIdx.x;
    const int row0 = blockIdx.x * RB;

    // ---- prologue: stage step-invariant weights, init OUT from x ----
    for (int e = tid; e < HD*HD; e += NTHREADS) {
        int n = e >> 7, k = e & 127;
        sWS1[n*WS_PITCH + k] = f2bf(Ws1[e]);
        sWS2[n*WS_PITCH + k] = f2bf(Ws2[e]);
    }
    if (tid < HD) { sBS1[tid] = bs1[tid]; sBS2[tid] = bs2[tid]; }
    for (int e = tid; e < RB*XD; e += NTHREADS) {
        int r = e >> 6, c = e & 63;
        sOUT[r*OUT_PITCH + c] = f2bf(x[(row0 + r)*XD + c]);
    }

    const int wave = tid >> 6;
    const int lane = tid & 63;
    const int lg   = lane >> 4;       // 0..3
    const int lc   = lane & 15;       // 0..15
    const int mrow = wave*16 + lc;    // block-local A row for fragments

    for (int i = 0; i < XD; ++i) {
        // ---- stage step i: masked Wi' (mask folded into weights), WiZ, bi, wf, bf, z ----
        {
            const float* Wi_i = Wi + (size_t)i * HD * (XD + 1);
            int k = tid & 63;
            float mc = (k == i) ? 0.0f : M[k*XD + i];   // parent mask col i, diag zeroed
            int nb = tid >> 6;
            #pragma unroll
            for (int j = 0; j < 16; ++j) {
                int n = nb + 8*j;
                sWI[n*WI_PITCH + k] = f2bf(Wi_i[n*(XD+1) + k] * mc);
            }
            if (tid < 128)      sWIZ[tid]     = Wi_i[tid*(XD+1) + XD];       // z column
            else if (tid < 256) sBI[tid-128]  = bi[i*HD + (tid-128)];
            else if (tid < 384) sWF[tid-256]  = wf[i*HD + (tid-256)];
            else                sZC[tid-384]  = z[(size_t)(row0 + tid-384)*XD + i];
            if (tid == 0) sBF[0] = bf[i];
        }
        __syncthreads();

        // ---- GEMM1: h1 = relu([xm | z] @ Wi_i^T + bi) ----
        short8 a0 = *(const short8*)(sOUT + mrow*OUT_PITCH + lg*8);
        short8 a1 = *(const short8*)(sOUT + mrow*OUT_PITCH + 32 + lg*8);
        float zv[4];
        #pragma unroll
        for (int j = 0; j < 4; ++j) zv[j] = sZC[wave*16 + lg*4 + j];

        #pragma unroll
        for (int t = 0; t < 8; ++t) {
            int n = t*16 + lc;
            short8 b0 = *(const short8*)(sWI + n*WI_PITCH + lg*8);
            short8 b1 = *(const short8*)(sWI + n*WI_PITCH + 32 + lg*8);
            f32x4 c = {0.f, 0.f, 0.f, 0.f};
            c = __builtin_amdgcn_mfma_f32_16x16x32_bf16(a0, b0, c, 0, 0, 0);
            c = __builtin_amdgcn_mfma_f32_16x16x32_bf16(a1, b1, c, 0, 0, 0);
            float wizn = sWIZ[n], bin = sBI[n];
            #pragma unroll
            for (int j = 0; j < 4; ++j) {
                float v = c[j] + zv[j]*wizn + bin;     // rank-1 z column + bias
                sH[(wave*16 + lg*4 + j)*WS_PITCH + n] = f2bf(fmaxf(v, 0.f));
            }
        }

        // ---- GEMM2: h2 = relu(h1 @ Ws1^T + bs1) (in-place ping-pong: A read to regs first) ----
        short8 A2[4];
        #pragma unroll
        for (int s = 0; s < 4; ++s)
            A2[s] = *(const short8*)(sH + mrow*WS_PITCH + s*32 + lg*8);
        #pragma unroll
        for (int t = 0; t < 8; ++t) {
            int n = t*16 + lc;
            f32x4 c = {0.f, 0.f, 0.f, 0.f};
            #pragma unroll
            for (int s = 0; s < 4; ++s) {
                short8 b = *(const short8*)(sWS1 + n*WS_PITCH + s*32 + lg*8);
                c = __builtin_amdgcn_mfma_f32_16x16x32_bf16(A2[s], b, c, 0, 0, 0);
            }
            float bn = sBS1[n];
            #pragma unroll
            for (int j = 0; j < 4; ++j)
                sH[(wave*16 + lg*4 + j)*WS_PITCH + n] = f2bf(fmaxf(c[j] + bn, 0.f));
        }

        // ---- GEMM3 + fused GEMV: o = sigmoid(relu(h2@Ws2^T+bs2) . wf_i + bf_i) ----
        short8 A3[4];
        #pragma unroll
        for (int s = 0; s < 4; ++s)
            A3[s] = *(const short8*)(sH + mrow*WS_PITCH + s*32 + lg*8);
        float op[4] = {0.f, 0.f, 0.f, 0.f};
        #pragma unroll
        for (int t = 0; t < 8; ++t) {
            int n = t*16 + lc;
            f32x4 c = {0.f, 0.f, 0.f, 0.f};
            #pragma unroll
            for (int s = 0; s < 4; ++s) {
                short8 b = *(const short8*)(sWS2 + n*WS_PITCH + s*32 + lg*8);
                c = __builtin_amdgcn_mfma_f32_16x16x32_bf16(A3[s], b, c, 0, 0, 0);
            }
            float bn = sBS2[n], wfn = sWF[n];
            #pragma unroll
            for (int j = 0; j < 4; ++j)
                op[j] += fmaxf(c[j] + bn, 0.f) * wfn;
        }
        // butterfly reduce over the 16 lanes (lc) holding different n (mod 16)
        #pragma unroll
        for (int m = 1; m < 16; m <<= 1) {
            #pragma unroll
            for (int j = 0; j < 4; ++j)
                op[j] += __shfl_xor(op[j], m, 64);
        }
        if (lc < 4) {
            float o = op[lc] + sBF[0];
            o = 1.0f / (1.0f + __expf(-o));
            sOUT[(wave*16 + lg*4 + lc)*OUT_PITCH + i] = f2bf(o);
        }
        __syncthreads();   // protect sWI/sZC/etc. before next step's staging
    }

    // ---- epilogue: OUT tile -> global f32 ----
    for (int e = tid; e < RB*XD; e += NTHREADS) {
        int r = e >> 6, c = e & 63;
        out[(size_t)(row0 + r)*XD + c] = bf2f(sOUT[r*OUT_PITCH + c]);
    }
}

extern "C" void kernel_launch(void* const* d_in, const int* in_sizes, int n_in,
                              void* d_out, int out_size, void* d_ws, size_t ws_size,
                              hipStream_t stream) {
    const float* x   = (const float*)d_in[0];
    const float* z   = (const float*)d_in[1];
    const float* M   = (const float*)d_in[2];
    const float* Wi  = (const float*)d_in[3];
    const float* bi  = (const float*)d_in[4];
    const float* Ws1 = (const float*)d_in[5];
    const float* bs1 = (const float*)d_in[6];
    const float* Ws2 = (const float*)d_in[7];
    const float* bs2 = (const float*)d_in[8];
    const float* wf  = (const float*)d_in[9];
    const float* bf  = (const float*)d_in[10];
    float* outp = (float*)d_out;

    hipFuncSetAttribute(reinterpret_cast<const void*>(gen_kernel),
                        hipFuncAttributeMaxDynamicSharedMemorySize, SMEM_BYTES);
    int nblocks = 65536 / RB;   // 512
    gen_kernel<<<nblocks, NTHREADS, SMEM_BYTES, stream>>>(
        x, z, M, Wi, bi, Ws1, bs1, Ws2, bs2, wf, bf, outp);
}

// Round 2
// 663.920 us; speedup vs baseline: 1.2326x; 1.2326x over previous
//
#include <hip/hip_runtime.h>

#define XD 64
#define HD 128
#define RB 128          // rows per block
#define NT 512          // 8 waves: 2 M-groups x 4 N-groups
#define BLOB 18432      // per-step blob: 16KB swizzled bf16 Wi' + 2KB scalars
#define N_STEP_CHUNKS 18

// LDS byte offsets
#define OFF_STEP0 0
#define OFF_STEP1 18432
#define OFF_H1    36864
#define OFF_H2    69632
#define OFF_WS2   102400
#define OFF_OUT   135168
#define OFF_ZC    151552
#define OFF_BS1   152576
#define OFF_BS2   153088
#define SMEM_BYTES 153600

typedef __attribute__((ext_vector_type(8))) short short8;
typedef __attribute__((ext_vector_type(4))) float f32x4;
typedef unsigned int u32;

__device__ __forceinline__ short f2bf(float f) {
    union { float f; unsigned u; } v; v.f = f;
    unsigned r = (v.u + 0x7FFFu + ((v.u >> 16) & 1u)) >> 16;  // RTNE
    return (short)r;
}
__device__ __forceinline__ float bf2f(short s) {
    union { float f; unsigned u; } v;
    v.u = ((unsigned)(unsigned short)s) << 16;
    return v.f;
}

// XOR-swizzled addressing: natural pitch, byte-offset bits 4..6 ^= row&7
__device__ __forceinline__ void* swz128(char* base, int row, int byteoff) {
    return base + row * 128 + (byteoff ^ ((row & 7) << 4));
}
__device__ __forceinline__ void* swz256(char* base, int row, int byteoff) {
    return base + row * 256 + (byteoff ^ ((row & 7) << 4));
}

__device__ __forceinline__ void gload16(const void* g, void* l) {
    __builtin_amdgcn_global_load_lds(
        (const __attribute__((address_space(1))) u32*)g,
        (__attribute__((address_space(3))) u32*)l, 16, 0, 0);
}

// ---------------- prep: fold mask into Wi, bf16-convert, pre-swizzle into blobs ----------------
__global__ void prep_kernel(const float* __restrict__ Wi, const float* __restrict__ M,
                            const float* __restrict__ bi, const float* __restrict__ wf,
                            const float* __restrict__ bf, char* __restrict__ ws)
{
    int idx = blockIdx.x * 256 + threadIdx.x;
    if (idx < XD * HD * 8) {                       // Wi' part: 64 steps x 128 n x 8 k-chunks
        int i  = idx >> 10;
        int n  = (idx >> 3) & 127;
        int kc = idx & 7;
        const float* src = Wi + ((size_t)i * HD + n) * (XD + 1) + kc * 8;
        short8 v;
        #pragma unroll
        for (int j = 0; j < 8; ++j) {
            int k = kc * 8 + j;
            float m = (k == i) ? 0.0f : M[k * XD + i];
            v[j] = f2bf(src[j] * m);
        }
        // pre-swizzled destination (linear LDS dest at stage time reproduces swz128 layout)
        char* dst = ws + (size_t)i * BLOB + n * 128 + ((kc * 16) ^ ((n & 7) << 4));
        *(short8*)dst = v;
    } else {
        int r = idx - XD * HD * 8;
        if (r < XD * HD) {                          // scalars: wiz / bi / wf / bf
            int i = r >> 7, n = r & 127;
            float* d = (float*)(ws + (size_t)i * BLOB + 16384);
            d[n]       = Wi[((size_t)i * HD + n) * (XD + 1) + XD];  // z-column weight
            d[128 + n] = bi[i * HD + n];
            d[256 + n] = wf[i * HD + n];
            if (n == 0) d[384] = bf[i];
        }
    }
}

// ---------------- main persistent-tile kernel ----------------
__global__ __launch_bounds__(NT, 1) void gen_kernel(
    const float* __restrict__ x,   const float* __restrict__ z,
    const float* __restrict__ Ws1, const float* __restrict__ Ws2,
    const float* __restrict__ bs1, const float* __restrict__ bs2,
    const char*  __restrict__ blob, float* __restrict__ out)
{
    extern __shared__ char smem[];
    const int tid  = threadIdx.x;
    const int row0 = blockIdx.x * RB;
    const int wave = tid >> 6, lane = tid & 63;
    const int lg = lane >> 4, lc = lane & 15;
    const int wm = wave >> 2, wn = wave & 3;    // 2 M-groups x 4 N-groups

    char*  sH1  = smem + OFF_H1;
    char*  sH2  = smem + OFF_H2;
    char*  sWS2 = smem + OFF_WS2;
    char*  sOUT = smem + OFF_OUT;
    float* sBS1 = (float*)(smem + OFF_BS1);
    float* sBS2 = (float*)(smem + OFF_BS2);

    // ---- prologue ----
    for (int c = wave; c < N_STEP_CHUNKS; c += 8)                      // blob 0 -> STEP0
        gload16(blob + c * 1024 + lane * 16, smem + OFF_STEP0 + c * 1024);
    if (tid < RB)                                                       // z col 0
        ((float*)(smem + OFF_ZC))[tid] = z[(size_t)(row0 + tid) * XD + 0];
    for (int c = tid; c < RB * 8; c += NT) {                            // OUT <- x (bf16, swz)
        int r = c >> 3, kc = c & 7;
        const float* xs = x + (size_t)(row0 + r) * XD + kc * 8;
        short8 v;
        #pragma unroll
        for (int j = 0; j < 8; ++j) v[j] = f2bf(xs[j]);
        *(short8*)swz128(sOUT, r, kc * 16) = v;
    }
    for (int c = tid; c < HD * 16; c += NT) {                           // Ws2 -> LDS (bf16, swz)
        int n = c >> 4, kc = c & 15;
        const float* wsrc = Ws2 + n * HD + kc * 8;
        short8 v;
        #pragma unroll
        for (int j = 0; j < 8; ++j) v[j] = f2bf(wsrc[j]);
        *(short8*)swz256(sWS2, n, kc * 16) = v;
    }
    if (tid < HD) { sBS1[tid] = bs1[tid]; sBS2[tid] = bs2[tid]; }

    short8 BW1[2][4];                                                   // Ws1 B-frags -> regs
    #pragma unroll
    for (int t = 0; t < 2; ++t) {
        int n = wn * 32 + t * 16 + lc;
        #pragma unroll
        for (int s = 0; s < 4; ++s) {
            const float* p = Ws1 + n * HD + s * 32 + lg * 8;
            #pragma unroll
            for (int j = 0; j < 8; ++j) BW1[t][s][j] = f2bf(p[j]);
        }
    }
    __syncthreads();

    float zreg = 0.f;
    for (int i = 0; i < XD; ++i) {
        char* sWIb = smem + ((i & 1) ? OFF_STEP1 : OFF_STEP0);
        char* sWIn = smem + ((i & 1) ? OFF_STEP0 : OFF_STEP1);
        const float* blobS = (const float*)(sWIb + 16384);
        float* zcur = (float*)(smem + OFF_ZC) + (i & 1) * 128;
        float* znxt = (float*)(smem + OFF_ZC) + ((i + 1) & 1) * 128;

        if (i + 1 < XD) {                                  // async-stage next blob + z
            const char* gb = blob + (size_t)(i + 1) * BLOB;
            for (int c = wave; c < N_STEP_CHUNKS; c += 8)
                gload16(gb + c * 1024 + lane * 16, sWIn + c * 1024);
            if (tid < RB) zreg = z[(size_t)(row0 + tid) * XD + (i + 1)];
        }

        // ---- G1 (N-split): h1 = relu([out*mask | z] @ Wi'^T + bi) ----
        short8 a0[4], a1[4], b0[2], b1[2];
        #pragma unroll
        for (int m = 0; m < 4; ++m) {
            int row = wm * 64 + m * 16 + lc;
            a0[m] = *(const short8*)swz128(sOUT, row, lg * 16);
            a1[m] = *(const short8*)swz128(sOUT, row, 64 + lg * 16);
        }
        #pragma unroll
        for (int t = 0; t < 2; ++t) {
            int n = wn * 32 + t * 16 + lc;
            b0[t] = *(const short8*)swz128(sWIb, n, lg * 16);
            b1[t] = *(const short8*)swz128(sWIb, n, 64 + lg * 16);
        }
        float zrow[4][4];
        #pragma unroll
        for (int m = 0; m < 4; ++m) {
            f32x4 zv = *(const f32x4*)&zcur[wm * 64 + m * 16 + lg * 4];
            #pragma unroll
            for (int j = 0; j < 4; ++j) zrow[m][j] = zv[j];
        }
        #pragma unroll
        for (int t = 0; t < 2; ++t) {
            int n = wn * 32 + t * 16 + lc;
            float wizn = blobS[n], bin = blobS[128 + n];
            #pragma unroll
            for (int m = 0; m < 4; ++m) {
                f32x4 c = {0.f, 0.f, 0.f, 0.f};
                c = __builtin_amdgcn_mfma_f32_16x16x32_bf16(a0[m], b0[t], c, 0, 0, 0);
                c = __builtin_amdgcn_mfma_f32_16x16x32_bf16(a1[m], b1[t], c, 0, 0, 0);
                #pragma unroll
                for (int j = 0; j < 4; ++j) {
                    int row = wm * 64 + m * 16 + lg * 4 + j;
                    float v = c[j] + zrow[m][j] * wizn + bin;
                    *(short*)swz256(sH1, row, 2 * n) = f2bf(fmaxf(v, 0.f));
                }
            }
        }
        __syncthreads();   // bar1

        // ---- G2 (N-split, Ws1 register-resident): h2 = relu(h1 @ Ws1^T + bs1) ----
        #pragma unroll
        for (int m = 0; m < 4; ++m) {
            int row = wm * 64 + m * 16 + lc;
            short8 A2[4];
            #pragma unroll
            for (int s = 0; s < 4; ++s)
                A2[s] = *(const short8*)swz256(sH1, row, s * 64 + lg * 16);
            #pragma unroll
            for (int t = 0; t < 2; ++t) {
                f32x4 c = {0.f, 0.f, 0.f, 0.f};
                #pragma unroll
                for (int s = 0; s < 4; ++s)
                    c = __builtin_amdgcn_mfma_f32_16x16x32_bf16(A2[s], BW1[t][s], c, 0, 0, 0);
                int n = wn * 32 + t * 16 + lc;
                float bn = sBS1[n];
                #pragma unroll
                for (int j = 0; j < 4; ++j) {
                    int wrow = wm * 64 + m * 16 + lg * 4 + j;
                    *(short*)swz256(sH2, wrow, 2 * n) = f2bf(fmaxf(c[j] + bn, 0.f));
                }
            }
        }
        __syncthreads();   // bar2

        // ---- G3 (M-split) + fused GEMV + sigmoid -> OUT col i ----
        {
            int mrow = wave * 16 + lc;
            short8 A3[4];
            #pragma unroll
            for (int s = 0; s < 4; ++s)
                A3[s] = *(const short8*)swz256(sH2, mrow, s * 64 + lg * 16);
            float op[4] = {0.f, 0.f, 0.f, 0.f};
            #pragma unroll
            for (int tp = 0; tp < 8; ++tp) {
                int n = tp * 16 + lc;
                f32x4 c = {0.f, 0.f, 0.f, 0.f};
                #pragma unroll
                for (int s = 0; s < 4; ++s) {
                    short8 b = *(const short8*)swz256(sWS2, n, s * 64 + lg * 16);
                    c = __builtin_amdgcn_mfma_f32_16x16x32_bf16(A3[s], b, c, 0, 0, 0);
                }
                float bn = sBS2[n], wfn = blobS[256 + n];
                #pragma unroll
                for (int j = 0; j < 4; ++j)
                    op[j] += fmaxf(c[j] + bn, 0.f) * wfn;
            }
            #pragma unroll
            for (int msk = 1; msk < 16; msk <<= 1) {
                #pragma unroll
                for (int j = 0; j < 4; ++j)
                    op[j] += __shfl_xor(op[j], msk, 64);
            }
            if (i + 1 < XD && tid < RB) znxt[tid] = zreg;   // commit prefetched z
            if (lc < 4) {
                float o = op[lc] + blobS[384];
                o = 1.0f / (1.0f + __expf(-o));
                int row = wave * 16 + lg * 4 + lc;
                *(short*)swz128(sOUT, row, 2 * i) = f2bf(o);
            }
        }
        __syncthreads();   // bar3 (drains global_load_lds staging too)
    }

    // ---- epilogue ----
    for (int c = tid; c < RB * 8; c += NT) {
        int r = c >> 3, kc = c & 7;
        short8 v = *(const short8*)swz128(sOUT, r, kc * 16);
        float* o = out + (size_t)(row0 + r) * XD + kc * 8;
        #pragma unroll
        for (int j = 0; j < 8; ++j) o[j] = bf2f(v[j]);
    }
}

extern "C" void kernel_launch(void* const* d_in, const int* in_sizes, int n_in,
                              void* d_out, int out_size, void* d_ws, size_t ws_size,
                              hipStream_t stream) {
    const float* x   = (const float*)d_in[0];
    const float* z   = (const float*)d_in[1];
    const float* M   = (const float*)d_in[2];
    const float* Wi  = (const float*)d_in[3];
    const float* bi  = (const float*)d_in[4];
    const float* Ws1 = (const float*)d_in[5];
    const float* bs1 = (const float*)d_in[6];
    const float* Ws2 = (const float*)d_in[7];
    const float* bs2 = (const float*)d_in[8];
    const float* wf  = (const float*)d_in[9];
    const float* bf  = (const float*)d_in[10];
    float* outp = (float*)d_out;
    char*  ws   = (char*)d_ws;

    prep_kernel<<<288, 256, 0, stream>>>(Wi, M, bi, wf, bf, ws);

    hipFuncSetAttribute(reinterpret_cast<const void*>(gen_kernel),
                        hipFuncAttributeMaxDynamicSharedMemorySize, SMEM_BYTES);
    gen_kernel<<<65536 / RB, NT, SMEM_BYTES, stream>>>(
        x, z, Ws1, Ws2, bs1, bs2, ws, outp);
}